// Round 8
// baseline (36.524 us; speedup 1.0000x reference)
//
#include <hip/hip_runtime.h>

// AdLIF neuron scan, producer/consumer two-kernel structure.
//
//  Kernel A (scan): 512 blocks x 256 threads (4 waves) per 64 channels.
//    - Wave 0 (consumer): runs the 512-step recurrence reading x from LDS,
//      bitpacks spikes, 2 u32 stores per 64-step tile to ws [word][chan].
//      Its vmcnt FIFO is essentially empty -> no load stalls ever.
//    - Waves 1-3 (producers): stage 64t x 64ch tiles into a 4-deep LDS ring
//      with dwordx4 loads (1 KB per instruction, 4x bytes per vmem FIFO slot).
//      6 producer waves/CU x ~8 outstanding x 1KB ~= 48 KB in flight per CU
//      vs ~4 KB in the old 1-wave-per-channel design (the round-7 limiter).
//    - Ring-4 + one __syncthreads per tile: producer for tile k+3 fills
//      buf[(k+3)&3] while consumer drains buf[k&3]; no overwrite hazard.
//  Kernel B (expand): reads 2 MB packed bits, writes f32 output as float4 NT
//    stores (proven at the write roofline in rounds 6-7).
//
// FP order matches the JAX reference exactly (mul then add, round-to-nearest,
// NO fma contraction) so spike decisions are bit-stable vs the reference.

#define T_STEPS 512
#define D_DIM   1024
#define N_CHAN  32768               // B * D
#define T_TILE  64
#define N_TILES (T_STEPS / T_TILE)  // 8
#define LDS_PITCH 68                // 64 + 4 pad (dwords) -> conflict-light

// f32(np.exp(-1/20)), f32(np.exp(-1/200))
#define ALPHA_MEM 0.9512294245007141f
#define ALPHA_ADP 0.9950124791926823f

typedef float f32x4 __attribute__((ext_vector_type(4)));

__device__ __forceinline__ bool adlif_step(float xv, float& v, float& a) {
    // v = alpha_mem * v + x_t
    v = __fadd_rn(__fmul_rn(ALPHA_MEM, v), xv);
    // cur_thr = THRESHOLD + BETA * a  (1.0 + 0.1*a)
    float cur = __fadd_rn(1.0f, __fmul_rn(0.1f, a));
    // s = (v - cur_thr >= THRESHOLD)   -- threshold counts twice, per ref
    float u = __fsub_rn(v, cur);
    bool fired = (u >= 1.0f);
    float s = fired ? 1.0f : 0.0f;
    // a = alpha_adp * a + s
    a = __fadd_rn(__fmul_rn(ALPHA_ADP, a), s);
    // v = v - s * THRESHOLD  (THRESHOLD = 1, exact)
    v = __fsub_rn(v, s);
    return fired;
}

// Producer: load one 64t x 64ch tile (17 KB) with 16 dwordx4 instructions.
// xb points at x[b, 0, dgrp*64]. Lane L: rows r0=L>>4 (+4 per instr),
// channels m=(L&15)*4 .. +3 (16 B contiguous per lane).
__device__ __forceinline__ void load_tile(const float* __restrict__ xb, int t0,
                                          int lane, float (*buf)[LDS_PITCH]) {
    const int r0 = lane >> 4;            // 0..3
    const int m  = lane & 15;            // 0..15
    const float* src = xb + (size_t)(t0 + r0) * D_DIM + m * 4;
    f32x4 v[16];
#pragma unroll
    for (int i = 0; i < 16; ++i)
        v[i] = *reinterpret_cast<const f32x4*>(src + (size_t)i * 4 * D_DIM);
#pragma unroll
    for (int i = 0; i < 16; ++i)
        *reinterpret_cast<f32x4*>(&buf[i * 4 + r0][m * 4]) = v[i];
}

// ---------------- Kernel A: scan + bitpack ----------------
__global__ __launch_bounds__(256) void adlif_scan(const float* __restrict__ x,
                                                  unsigned* __restrict__ wsbits) {
    __shared__ float tiles[4][T_TILE][LDS_PITCH];    // 68 KB ring

    const int lane = threadIdx.x & 63;
    const int wave = threadIdx.x >> 6;               // 0..3
    const int bid  = blockIdx.x;                     // 0..511
    const int b    = bid >> 4;                       // 0..31
    const int dgrp = bid & 15;                       // 0..15
    const float* xb = x + (size_t)b * (T_STEPS * D_DIM) + dgrp * 64;
    const int chan = (b << 10) + dgrp * 64 + lane;   // consumer's channel

    // prologue: producers fill tiles 0,1,2
    if (wave >= 1) {
        const int t = wave - 1;                      // tile (t%3)+1 == wave
        load_tile(xb, t * T_TILE, lane, tiles[t]);
    }
    __syncthreads();

    float v = 0.0f, a = 0.0f;

    for (int k = 0; k < N_TILES; ++k) {              // rolled, 8 iterations
        if (wave == 0) {
            // ---- consumer: 64 steps from tiles[k&3] ----
            unsigned wlo = 0u, whi = 0u;
#pragma unroll
            for (int j = 0; j < T_TILE; ++j) {
                const float xv = tiles[k & 3][j][lane];
                const bool f = adlif_step(xv, v, a);
                if (j < 32) wlo |= ((unsigned)f) << j;
                else        whi |= ((unsigned)f) << (j - 32);
            }
            wsbits[(size_t)(k * 2 + 0) * N_CHAN + chan] = wlo;
            wsbits[(size_t)(k * 2 + 1) * N_CHAN + chan] = whi;
        } else {
            // ---- producer: stage tile k+3 (ring slot (k+3)&3) ----
            const int t = k + 3;
            if (t < N_TILES && wave == (t % 3) + 1)
                load_tile(xb, t * T_TILE, lane, tiles[t & 3]);
        }
        __syncthreads();
    }
}

// ---------------- Kernel B: bit expand + f32 store ----------------
// grid: 32 (b) x 16 (word) = 512 blocks, 256 threads.
__global__ __launch_bounds__(256) void adlif_expand(const unsigned* __restrict__ wsbits,
                                                    float* __restrict__ out) {
    const int b = blockIdx.x >> 4;
    const int w = blockIdx.x & 15;
    const int d0 = threadIdx.x * 4;                  // 4 channels per thread
    const int c0 = (b << 10) + d0;

    const uint4 wd = *reinterpret_cast<const uint4*>(&wsbits[(size_t)w * N_CHAN + c0]);

    float* op = out + ((size_t)b * T_STEPS + w * 32) * D_DIM + d0;

#pragma unroll
    for (int k = 0; k < 32; ++k) {
        f32x4 val;
        val.x = (float)((wd.x >> k) & 1u);
        val.y = (float)((wd.y >> k) & 1u);
        val.z = (float)((wd.z >> k) & 1u);
        val.w = (float)((wd.w >> k) & 1u);
        __builtin_nontemporal_store(val, (f32x4*)(op + (size_t)k * D_DIM));
    }
}

// ---------------- Fallback (ws too small): round-5 single kernel ----------------
__global__ __launch_bounds__(64) void adlif_single(const float* __restrict__ x,
                                                   float* __restrict__ out) {
    __shared__ unsigned sbits[64 * 17];
    const int tid = threadIdx.x;
    const int idx = blockIdx.x * 64 + tid;
    const int b = idx >> 10;
    const int d = idx & (D_DIM - 1);
    const size_t base = (size_t)b * (T_STEPS * D_DIM) + d;
    const float* xp = x + base;
    float* op = out + base;

    float v = 0.0f, a = 0.0f;
    constexpr int U = 32;
    float buf0[U], buf1[U];
#pragma unroll
    for (int i = 0; i < U; ++i) buf0[i] = xp[i * D_DIM];
    for (int it = 0; it < T_STEPS / (2 * U); ++it) {
        const int t0 = it * 2 * U;
#pragma unroll
        for (int i = 0; i < U; ++i) buf1[i] = xp[(t0 + U + i) * D_DIM];
        unsigned wA = 0u;
#pragma unroll
        for (int i = 0; i < U; ++i) { bool f = adlif_step(buf0[i], v, a); wA |= ((unsigned)f) << i; }
        sbits[tid * 17 + it * 2] = wA;
        if (it + 1 < T_STEPS / (2 * U)) {
#pragma unroll
            for (int i = 0; i < U; ++i) buf0[i] = xp[(t0 + 2 * U + i) * D_DIM];
        }
        unsigned wB = 0u;
#pragma unroll
        for (int i = 0; i < U; ++i) { bool f = adlif_step(buf1[i], v, a); wB |= ((unsigned)f) << i; }
        sbits[tid * 17 + it * 2 + 1] = wB;
    }
    for (int w = 0; w < T_STEPS / 32; ++w) {
        const unsigned wb = sbits[tid * 17 + w];
#pragma unroll
        for (int k = 0; k < 32; ++k) {
            float s = (float)((wb >> k) & 1u);
            __builtin_nontemporal_store(s, &op[(size_t)(w * 32 + k) * D_DIM]);
        }
    }
}

extern "C" void kernel_launch(void* const* d_in, const int* in_sizes, int n_in,
                              void* d_out, int out_size, void* d_ws, size_t ws_size,
                              hipStream_t stream) {
    const float* x = (const float*)d_in[0];
    float* out = (float*)d_out;

    const size_t need = (size_t)N_CHAN * (T_STEPS / 32) * sizeof(unsigned);  // 2 MB

    if (ws_size >= need) {
        unsigned* wsbits = (unsigned*)d_ws;
        adlif_scan<<<512, 256, 0, stream>>>(x, wsbits);
        adlif_expand<<<32 * 16, 256, 0, stream>>>(wsbits, out);
    } else {
        adlif_single<<<N_CHAN / 64, 64, 0, stream>>>(x, out);
    }
}

// Round 9
// 27.442 us; speedup vs baseline: 1.3309x; 1.3309x over previous
//
#include <hip/hip_runtime.h>

// AdLIF neuron scan, fully-fused producer/consumer/writer single kernel.
//
// 512 blocks x 512 threads (8 waves), one block owns 64 channels (b, dgrp):
//   wave 0   : consumer -- 512-step recurrence reading x-tiles from an LDS
//              ring, bitpacks spikes into a tiny LDS double-buffer (2 u32
//              per channel per 64-step tile). Never touches global memory.
//   waves 1-3: producers -- stage 64t x 64ch x-tiles into a 4-deep LDS ring
//              with dwordx4 loads (1 KB/instr), running 3 tiles ahead.
//   waves 4-7: writers -- expand tile k-1's bits to f32 and emit float4
//              non-temporal stores (the regime measured at ~6.5 TB/s).
// One __syncthreads per tile; 9 pipelined iterations (8 tiles + drain).
// Reads, recurrence, and writes all proceed concurrently; irreducible
// traffic 134 MB -> ~21 us floor at 6.3 TB/s.
//
// FP order matches the JAX reference exactly (mul then add, round-to-nearest,
// NO fma contraction) so spike decisions are bit-stable vs the reference.

#define T_STEPS 512
#define D_DIM   1024
#define T_TILE  64
#define N_TILES (T_STEPS / T_TILE)   // 8
#define LDS_PITCH 68                 // 64 + 4 pad (dwords)

// f32(np.exp(-1/20)), f32(np.exp(-1/200))
#define ALPHA_MEM 0.9512294245007141f
#define ALPHA_ADP 0.9950124791926823f

typedef float f32x4 __attribute__((ext_vector_type(4)));

__device__ __forceinline__ bool adlif_step(float xv, float& v, float& a) {
    // v = alpha_mem * v + x_t
    v = __fadd_rn(__fmul_rn(ALPHA_MEM, v), xv);
    // cur_thr = THRESHOLD + BETA * a  (1.0 + 0.1*a)
    float cur = __fadd_rn(1.0f, __fmul_rn(0.1f, a));
    // s = (v - cur_thr >= THRESHOLD)   -- threshold counts twice, per ref
    float u = __fsub_rn(v, cur);
    bool fired = (u >= 1.0f);
    float s = fired ? 1.0f : 0.0f;
    // a = alpha_adp * a + s
    a = __fadd_rn(__fmul_rn(ALPHA_ADP, a), s);
    // v = v - s * THRESHOLD  (THRESHOLD = 1, exact)
    v = __fsub_rn(v, s);
    return fired;
}

// Producer: load one 64t x 64ch tile with 16 dwordx4 loads per wave.
// Lane L: rows r0=L>>4 (+4 per instr), channels m=(L&15)*4 .. +3.
__device__ __forceinline__ void load_tile(const float* __restrict__ xb, int t0,
                                          int lane, float (*buf)[LDS_PITCH]) {
    const int r0 = lane >> 4;            // 0..3
    const int m  = lane & 15;            // 0..15
    const float* src = xb + (size_t)(t0 + r0) * D_DIM + m * 4;
    f32x4 v[16];
#pragma unroll
    for (int i = 0; i < 16; ++i)
        v[i] = *reinterpret_cast<const f32x4*>(src + (size_t)i * 4 * D_DIM);
#pragma unroll
    for (int i = 0; i < 16; ++i)
        *reinterpret_cast<f32x4*>(&buf[i * 4 + r0][m * 4]) = v[i];
}

__global__ __launch_bounds__(512) void adlif_fused(const float* __restrict__ x,
                                                   float* __restrict__ out) {
    __shared__ float    tiles[4][T_TILE][LDS_PITCH]; // 68 KB input ring
    __shared__ unsigned sbits[2][64][2];             // 1 KB spike-bit dbuf

    const int lane = threadIdx.x & 63;
    const int wave = threadIdx.x >> 6;               // 0..7
    const int bid  = blockIdx.x;                     // 0..511
    const int b    = bid >> 4;                       // 0..31
    const int dgrp = bid & 15;                       // 0..15
    const float* xb = x   + (size_t)b * (T_STEPS * D_DIM) + dgrp * 64;
    float*       ob = out + (size_t)b * (T_STEPS * D_DIM) + dgrp * 64;

    // prologue: producers fill tiles 0,1,2
    if (wave >= 1 && wave <= 3)
        load_tile(xb, (wave - 1) * T_TILE, lane, tiles[wave - 1]);
    __syncthreads();

    float v = 0.0f, a = 0.0f;

    for (int k = 0; k <= N_TILES; ++k) {             // 9 pipelined iterations
        if (wave == 0) {
            // ---- consumer: 64 steps of tile k -> 2 packed words in LDS ----
            if (k < N_TILES) {
                unsigned wlo = 0u, whi = 0u;
#pragma unroll
                for (int j = 0; j < T_TILE; ++j) {
                    const float xv = tiles[k & 3][j][lane];
                    const bool f = adlif_step(xv, v, a);
                    if (j < 32) wlo |= ((unsigned)f) << j;
                    else        whi |= ((unsigned)f) << (j - 32);
                }
                sbits[k & 1][lane][0] = wlo;
                sbits[k & 1][lane][1] = whi;
            }
        } else if (wave <= 3) {
            // ---- producer: stage tile k+3 into ring slot (k+3)&3 ----
            const int t = k + 3;
            if (t < N_TILES && wave == (t % 3) + 1)
                load_tile(xb, t * T_TILE, lane, tiles[t & 3]);
        } else {
            // ---- writers: expand tile k-1 bits -> f32, NT float4 stores ----
            if (k >= 1) {
                const int kt = k - 1;
                const int r0 = (wave - 4) * 16;      // this wave's 16 rows
                const int c0 = (lane & 15) * 4;      // 4 channels per lane
                const int rl = lane >> 4;            // 0..3 row-within-instr
                const int half = (r0 >= 32) ? 1 : 0; // wlo or whi
                const unsigned w0 = sbits[kt & 1][c0 + 0][half];
                const unsigned w1 = sbits[kt & 1][c0 + 1][half];
                const unsigned w2 = sbits[kt & 1][c0 + 2][half];
                const unsigned w3 = sbits[kt & 1][c0 + 3][half];
#pragma unroll
                for (int i = 0; i < 4; ++i) {
                    const int r = r0 + i * 4 + rl;   // absolute row in tile
                    const int bitpos = r & 31;
                    f32x4 val;
                    val.x = (float)((w0 >> bitpos) & 1u);
                    val.y = (float)((w1 >> bitpos) & 1u);
                    val.z = (float)((w2 >> bitpos) & 1u);
                    val.w = (float)((w3 >> bitpos) & 1u);
                    __builtin_nontemporal_store(
                        val, (f32x4*)(ob + (size_t)(kt * T_TILE + r) * D_DIM + c0));
                }
            }
        }
        __syncthreads();
    }
}

extern "C" void kernel_launch(void* const* d_in, const int* in_sizes, int n_in,
                              void* d_out, int out_size, void* d_ws, size_t ws_size,
                              hipStream_t stream) {
    const float* x = (const float*)d_in[0];
    float* out = (float*)d_out;

    const int total = in_sizes[0];            // B*T*D = 16777216
    const int channels = total / T_STEPS;     // B*D  = 32768
    const int blocks = channels / 64;         // 512 blocks x 8 waves

    adlif_fused<<<blocks, 512, 0, stream>>>(x, out);
}

// Round 10
// 26.084 us; speedup vs baseline: 1.4002x; 1.0521x over previous
//
#include <hip/hip_runtime.h>

// AdLIF neuron scan, fused producer/consumer/writer single kernel (round 10:
// ring 4 -> 3, pitch 68 -> 66: LDS 70.7 -> 51.7 KB => 3 blocks/CU instead of
// 2, +50% memory-issuing waves per CU).
//
// 512 blocks x 512 threads (8 waves), one block owns 64 channels (b, dgrp):
//   wave 0   : consumer -- 512-step recurrence reading x-tiles from a 3-deep
//              LDS ring, bitpacks spikes into a tiny LDS double-buffer.
//   waves 1-3: producers -- stage 64t x 64ch x-tiles into the ring with
//              dwordx4 loads (1 KB/instr), running 2 tiles ahead (2 full
//              tile-periods ~ 2x6400cy >> ~900cy HBM latency).
//   waves 4-7: writers -- expand tile k-1's bits to f32, float4 NT stores.
// One __syncthreads per tile; 9 pipelined iterations (8 tiles + drain).
//
// FP order matches the JAX reference exactly (mul then add, round-to-nearest,
// NO fma contraction) so spike decisions are bit-stable vs the reference.

#define T_STEPS 512
#define D_DIM   1024
#define T_TILE  64
#define N_TILES (T_STEPS / T_TILE)   // 8
#define RING    3
#define LDS_PITCH 66                 // 64 + 2 pad (dwords)

// f32(np.exp(-1/20)), f32(np.exp(-1/200))
#define ALPHA_MEM 0.9512294245007141f
#define ALPHA_ADP 0.9950124791926823f

typedef float f32x4 __attribute__((ext_vector_type(4)));

__device__ __forceinline__ bool adlif_step(float xv, float& v, float& a) {
    // v = alpha_mem * v + x_t
    v = __fadd_rn(__fmul_rn(ALPHA_MEM, v), xv);
    // cur_thr = THRESHOLD + BETA * a  (1.0 + 0.1*a)
    float cur = __fadd_rn(1.0f, __fmul_rn(0.1f, a));
    // s = (v - cur_thr >= THRESHOLD)   -- threshold counts twice, per ref
    float u = __fsub_rn(v, cur);
    bool fired = (u >= 1.0f);
    float s = fired ? 1.0f : 0.0f;
    // a = alpha_adp * a + s
    a = __fadd_rn(__fmul_rn(ALPHA_ADP, a), s);
    // v = v - s * THRESHOLD  (THRESHOLD = 1, exact)
    v = __fsub_rn(v, s);
    return fired;
}

// Producer: load one 64t x 64ch tile with 16 dwordx4 loads per wave.
// Lane L: rows r0=L>>4 (+4 per instr), channels m=(L&15)*4 .. +3.
__device__ __forceinline__ void load_tile(const float* __restrict__ xb, int t0,
                                          int lane, float (*buf)[LDS_PITCH]) {
    const int r0 = lane >> 4;            // 0..3
    const int m  = lane & 15;            // 0..15
    const float* src = xb + (size_t)(t0 + r0) * D_DIM + m * 4;
    f32x4 v[16];
#pragma unroll
    for (int i = 0; i < 16; ++i)
        v[i] = *reinterpret_cast<const f32x4*>(src + (size_t)i * 4 * D_DIM);
#pragma unroll
    for (int i = 0; i < 16; ++i)
        *reinterpret_cast<f32x4*>(&buf[i * 4 + r0][m * 4]) = v[i];
}

__global__ __launch_bounds__(512) void adlif_fused(const float* __restrict__ x,
                                                   float* __restrict__ out) {
    __shared__ float    tiles[RING][T_TILE][LDS_PITCH]; // 50688 B input ring
    __shared__ unsigned sbits[2][64][2];                // 1 KB spike-bit dbuf

    const int lane = threadIdx.x & 63;
    const int wave = threadIdx.x >> 6;               // 0..7
    const int bid  = blockIdx.x;                     // 0..511
    const int b    = bid >> 4;                       // 0..31
    const int dgrp = bid & 15;                       // 0..15
    const float* xb = x   + (size_t)b * (T_STEPS * D_DIM) + dgrp * 64;
    float*       ob = out + (size_t)b * (T_STEPS * D_DIM) + dgrp * 64;

    // prologue: producers fill tiles 0,1 (lookahead 2)
    if (wave == 1) load_tile(xb, 0 * T_TILE, lane, tiles[0]);
    if (wave == 2) load_tile(xb, 1 * T_TILE, lane, tiles[1]);
    __syncthreads();

    float v = 0.0f, a = 0.0f;

    for (int k = 0; k <= N_TILES; ++k) {             // 9 pipelined iterations
        if (wave == 0) {
            // ---- consumer: 64 steps of tile k -> 2 packed words in LDS ----
            if (k < N_TILES) {
                unsigned wlo = 0u, whi = 0u;
#pragma unroll
                for (int j = 0; j < T_TILE; ++j) {
                    const float xv = tiles[k % RING][j][lane];
                    const bool f = adlif_step(xv, v, a);
                    if (j < 32) wlo |= ((unsigned)f) << j;
                    else        whi |= ((unsigned)f) << (j - 32);
                }
                sbits[k & 1][lane][0] = wlo;
                sbits[k & 1][lane][1] = whi;
            }
        } else if (wave <= 3) {
            // ---- producer: stage tile k+2 into ring slot (k+2)%3 ----
            const int t = k + 2;
            if (t < N_TILES && wave == (t % 3) + 1)
                load_tile(xb, t * T_TILE, lane, tiles[t % RING]);
        } else {
            // ---- writers: expand tile k-1 bits -> f32, NT float4 stores ----
            if (k >= 1) {
                const int kt = k - 1;
                const int r0 = (wave - 4) * 16;      // this wave's 16 rows
                const int c0 = (lane & 15) * 4;      // 4 channels per lane
                const int rl = lane >> 4;            // 0..3 row-within-instr
                const int half = (r0 >= 32) ? 1 : 0; // wlo or whi
                const unsigned w0 = sbits[kt & 1][c0 + 0][half];
                const unsigned w1 = sbits[kt & 1][c0 + 1][half];
                const unsigned w2 = sbits[kt & 1][c0 + 2][half];
                const unsigned w3 = sbits[kt & 1][c0 + 3][half];
#pragma unroll
                for (int i = 0; i < 4; ++i) {
                    const int r = r0 + i * 4 + rl;   // absolute row in tile
                    const int bitpos = r & 31;
                    f32x4 val;
                    val.x = (float)((w0 >> bitpos) & 1u);
                    val.y = (float)((w1 >> bitpos) & 1u);
                    val.z = (float)((w2 >> bitpos) & 1u);
                    val.w = (float)((w3 >> bitpos) & 1u);
                    __builtin_nontemporal_store(
                        val, (f32x4*)(ob + (size_t)(kt * T_TILE + r) * D_DIM + c0));
                }
            }
        }
        __syncthreads();
    }
}

extern "C" void kernel_launch(void* const* d_in, const int* in_sizes, int n_in,
                              void* d_out, int out_size, void* d_ws, size_t ws_size,
                              hipStream_t stream) {
    const float* x = (const float*)d_in[0];
    float* out = (float*)d_out;

    const int total = in_sizes[0];            // B*T*D = 16777216
    const int channels = total / T_STEPS;     // B*D  = 32768
    const int blocks = channels / 64;         // 512 blocks x 8 waves

    adlif_fused<<<blocks, 512, 0, stream>>>(x, out);
}